// Round 8
// baseline (129.128 us; speedup 1.0000x reference)
//
#include <hip/hip_runtime.h>
#include <math.h>

// Spherical voxelization: points [B,N,3] f32 -> hist [B,1,5,30,15] f32
// B=16, N=65536, bins = 5*30*15 = 2250.
// R8: R7's fixed-point native-atomic scheme (fp32 atomicAdd = CAS loop was
// the ~40us invariant; u32 ds_add/global_add are single native instrs), plus:
//  - fused tail: last block per batch (device-scope arrival counter)
//    converts u32 accumulators -> float d_out; fx_convert dispatch dropped.
//  - BLOCK=512, PPB=2048 -> 512 blocks: flush atomics & LDS zeroing halved,
//    still 16 waves/CU.

constexpr int RAD_N = 5, AZI_N = 30, ELE_N = 15;
constexpr int BINS  = RAD_N * AZI_N * ELE_N;   // 2250
constexpr int BLOCK = 512;
constexpr int PPT   = 4;                       // points per thread
constexpr int PPB   = BLOCK * PPT;             // 2048
constexpr float FX_SCALE = 2097152.0f;         // 2^21
constexpr float FX_INV   = 1.0f / 2097152.0f;

__device__ __forceinline__ float fast_atan2_02pi(float y, float x) {
    const float PI_F     = 3.14159265358979f;
    const float TWO_PI_F = 6.28318530717959f;
    const float HALF_PI  = 1.57079632679490f;
    float ax = fabsf(x), ay = fabsf(y);
    float mx = fmaxf(ax, ay), mn = fminf(ax, ay);
    float t  = mn * __builtin_amdgcn_rcpf(mx);
    float t2 = t * t;
    float p = -0.01172120f;
    p = __builtin_fmaf(p, t2,  0.05265332f);
    p = __builtin_fmaf(p, t2, -0.11643287f);
    p = __builtin_fmaf(p, t2,  0.19354346f);
    p = __builtin_fmaf(p, t2, -0.33262347f);
    p = __builtin_fmaf(p, t2,  0.99997726f);
    float th = t * p;                          // [0, pi/4]
    th = (ay > ax) ? (HALF_PI - th) : th;      // [0, pi/2]
    th = (x < 0.0f) ? (PI_F - th) : th;        // [0, pi]
    th = (y < 0.0f) ? (TWO_PI_F - th) : th;    // [0, 2pi)
    return th;
}

__device__ __forceinline__ float fast_acos(float x) {
    const float PI_F = 3.14159265358979f;
    float a = fabsf(x);
    float p = -0.0012624911f;
    p = __builtin_fmaf(p, a,  0.0066700901f);
    p = __builtin_fmaf(p, a, -0.0170881256f);
    p = __builtin_fmaf(p, a,  0.0308918810f);
    p = __builtin_fmaf(p, a, -0.0501743046f);
    p = __builtin_fmaf(p, a,  0.0889789874f);
    p = __builtin_fmaf(p, a, -0.2145988016f);
    p = __builtin_fmaf(p, a,  1.5707963050f);
    float s = __builtin_amdgcn_sqrtf(1.0f - a);
    float r = s * p;
    return (x < 0.0f) ? (PI_F - r) : r;
}

__device__ __forceinline__ unsigned to_fx(float w) {
    float v = __builtin_fmaf(w, FX_SCALE, 0.5f);
    return (unsigned)fmaxf(v, 0.0f);
}

__device__ __forceinline__ void process_point(float x, float y, float z,
                                              unsigned* hist) {
    const float TWO_PI_F = (float)(6.283185307179586);
    const float PI_F     = (float)(3.141592653589793);
    const float tr       = (float)(2.0 / 5.0);
    const float sr       = (float)(2.0 / 5.0 / 2.0);
    const float tr_p_sr  = (float)(0.4 + 0.2);
    const float rhi_lo   = (float)(2.0 - 0.2);
    const float DES_R_F  = 2.0f;
    const float ta       = (float)(6.283185307179586 / 30.0);
    const float te       = (float)(3.141592653589793 / 15.0);
    const float se       = (float)(3.141592653589793 / 30.0);
    const float te_p_se  = (float)(3.141592653589793 / 15.0 + 3.141592653589793 / 30.0);
    const float te075    = (float)(0.75 * (3.141592653589793 / 15.0));
    const float pi_m_se  = (float)(3.141592653589793 - 3.141592653589793 / 30.0);
    const float inv_tr   = (float)(5.0 / 2.0);
    const float inv_ta   = (float)(30.0 / 6.283185307179586);
    const float inv_te   = (float)(15.0 / 3.141592653589793);

    float r = __builtin_amdgcn_sqrtf(x * x + y * y + z * z);
    if (r > DES_R_F) return;   // all 8 weights exactly 0 in reference

    float azi = fast_atan2_02pi(y, x);
    float cz = z * __builtin_amdgcn_rcpf(fmaxf(r, 1e-12f));
    cz = fminf(fmaxf(cz, -1.0f), 1.0f);
    float ele = fast_acos(cz);

    // ---- radial ----
    int ra = (int)(r * inv_tr);
    if (ra > RAD_N - 1) ra = RAD_N - 1;
    float cra = ((float)ra + 0.5f) * tr;
    int rb = (r > cra) ? ra + 1 : ra - 1;
    rb = (rb < 0) ? 1 : ((rb > RAD_N - 1) ? RAD_N - 2 : rb);
    float dra = fabsf(r - cra);
    float drb = fabsf(r - ((float)rb + 0.5f) * tr);
    {
        bool lowR  = r < sr;
        bool highR = (r > rhi_lo);
        if (lowR) {
            dra = (dra <= sr) ? 0.0f : ((dra > tr && dra <= tr_p_sr) ? tr : dra);
            drb = (drb <= sr) ? 0.0f : ((drb > tr && drb <= tr_p_sr) ? tr : drb);
        }
        if (highR) {
            if (dra > tr && dra <= tr_p_sr) dra = tr;
            if (drb > tr && drb <= tr_p_sr) drb = tr;
        }
    }
    float wra = 1.0f - dra * inv_tr;
    float wrb = 1.0f - drb * inv_tr;

    // ---- azimuth (circular) ----
    int aa = (int)(azi * inv_ta);
    if (aa > AZI_N - 1) aa = AZI_N - 1;
    float caa = ((float)aa + 0.5f) * ta;
    int ab = (azi > caa) ? aa + 1 : aa - 1;
    ab = (ab < 0) ? AZI_N - 1 : ((ab > AZI_N - 1) ? 0 : ab);
    float daa = fabsf(azi - caa);
    daa = fminf(daa, TWO_PI_F - daa);
    float dab = fabsf(azi - ((float)ab + 0.5f) * ta);
    dab = fminf(dab, TWO_PI_F - dab);
    float waa = 1.0f - daa * inv_ta;
    float wab = 1.0f - dab * inv_ta;

    // ---- elevation ----
    int ea = (int)(ele * inv_te);
    if (ea > ELE_N - 1) ea = ELE_N - 1;
    float cea = ((float)ea + 0.5f) * te;
    int eb = (ele > cea) ? ea + 1 : ea - 1;
    eb = (eb < 0) ? 1 : ((eb > ELE_N - 1) ? ELE_N - 2 : eb);
    float dea = fabsf(ele - cea);
    float deb = fabsf(ele - ((float)eb + 0.5f) * te);
    {
        bool lowE  = ele < se;
        bool highE = (ele > pi_m_se) && (ele <= PI_F);
        if (lowE) {
            dea = (dea <= se) ? 0.0f : ((dea > te && dea <= te_p_se) ? te : dea);
            deb = (deb <= se) ? 0.0f : ((deb > te && deb <= te_p_se) ? te : deb);
        }
        if (highE) {
            dea = (dea <= te075) ? 0.0f : ((dea > te && dea <= te_p_se) ? te : dea);
            deb = (deb <= te075) ? 0.0f : ((deb > te && deb <= te_p_se) ? te : deb);
        }
    }
    float wea = 1.0f - dea * inv_te;
    float web = 1.0f - deb * inv_te;

    int rbase_a = ra * (AZI_N * ELE_N), rbase_b = rb * (AZI_N * ELE_N);
    int abase_a = aa * ELE_N,           abase_b = ab * ELE_N;
    float w_aa = wra * waa, w_ab = wra * wab;
    float w_ba = wrb * waa, w_bb = wrb * wab;

    atomicAdd(&hist[rbase_a + abase_a + ea], to_fx(w_aa * wea));
    atomicAdd(&hist[rbase_a + abase_a + eb], to_fx(w_aa * web));
    atomicAdd(&hist[rbase_a + abase_b + ea], to_fx(w_ab * wea));
    atomicAdd(&hist[rbase_a + abase_b + eb], to_fx(w_ab * web));
    atomicAdd(&hist[rbase_b + abase_a + ea], to_fx(w_ba * wea));
    atomicAdd(&hist[rbase_b + abase_a + eb], to_fx(w_ba * web));
    atomicAdd(&hist[rbase_b + abase_b + ea], to_fx(w_bb * wea));
    atomicAdd(&hist[rbase_b + abase_b + eb], to_fx(w_bb * web));
}

// ws layout: [0, B*BINS) u32 accumulators, [B*BINS, B*BINS+B) arrival counters
__global__ __launch_bounds__(BLOCK) void voxel_fused(
    const float* __restrict__ pts, unsigned* __restrict__ ws_u,
    float* __restrict__ out, int N, int blocksPerBatch)
{
    __shared__ unsigned hist[BINS];
    __shared__ int isLast;
    for (int j = threadIdx.x; j < BINS; j += BLOCK) hist[j] = 0u;
    __syncthreads();

    const int batch = blockIdx.x / blocksPerBatch;
    const int bib   = blockIdx.x % blocksPerBatch;
    const size_t batch_off = (size_t)batch * N;
    const int i0 = bib * PPB + (int)threadIdx.x * PPT;

    if (i0 + PPT <= N) {
        const float4* src = (const float4*)(pts + (batch_off + i0) * 3);
        float4 q0 = src[0];
        float4 q1 = src[1];
        float4 q2 = src[2];
        float X[PPT] = { q0.x, q0.w, q1.z, q2.y };
        float Y[PPT] = { q0.y, q1.x, q1.w, q2.z };
        float Z[PPT] = { q0.z, q1.y, q2.x, q2.w };
#pragma unroll
        for (int k = 0; k < PPT; ++k)
            process_point(X[k], Y[k], Z[k], hist);
    } else {
        for (int k = 0; k < PPT; ++k) {
            int i = i0 + k;
            if (i < N) {
                size_t p = (batch_off + i) * 3;
                process_point(pts[p], pts[p + 1], pts[p + 2], hist);
            }
        }
    }

    __syncthreads();
    unsigned* ob = ws_u + (size_t)batch * BINS;
    for (int j = threadIdx.x; j < BINS; j += BLOCK) {
        unsigned v = hist[j];
        if (v) atomicAdd(&ob[j], v);   // native device-scope global_atomic_add
    }

    // ---- arrival counter; last block per batch converts to float out ----
    __threadfence();   // make our flush atomics visible before signaling
    if (threadIdx.x == 0) {
        unsigned* ctr = ws_u + (size_t)16 * BINS + batch;
        unsigned prev = __hip_atomic_fetch_add(ctr, 1u, __ATOMIC_ACQ_REL,
                                               __HIP_MEMORY_SCOPE_AGENT);
        isLast = (prev == (unsigned)(blocksPerBatch - 1));
    }
    __syncthreads();
    if (isLast) {
        float* od = out + (size_t)batch * BINS;
        for (int j = threadIdx.x; j < BINS; j += BLOCK) {
            // agent-scope atomic load: coherent across XCDs (plain load could
            // hit a stale per-XCD L2 line)
            unsigned v = __hip_atomic_load(&ob[j], __ATOMIC_RELAXED,
                                           __HIP_MEMORY_SCOPE_AGENT);
            od[j] = (float)v * FX_INV;
        }
    }
}

extern "C" void kernel_launch(void* const* d_in, const int* in_sizes, int n_in,
                              void* d_out, int out_size, void* d_ws, size_t ws_size,
                              hipStream_t stream) {
    const float* pts = (const float*)d_in[0];
    float* out = (float*)d_out;

    const int B = 16;
    int total = in_sizes[0] / 3;                 // B*N
    int N = total / B;                           // 65536
    int blocksPerBatch = (N + PPB - 1) / PPB;    // 32
    int grid = B * blocksPerBatch;               // 512

    unsigned* ws_u = (unsigned*)d_ws;            // B*BINS accum + B counters
    size_t zero_bytes = ((size_t)B * BINS + B) * sizeof(unsigned);  // ~144.4 KB
    hipMemsetAsync(d_ws, 0, zero_bytes, stream);
    voxel_fused<<<dim3(grid), dim3(BLOCK), 0, stream>>>(pts, ws_u, out, N, blocksPerBatch);
}

// Round 9
// 69.986 us; speedup vs baseline: 1.8450x; 1.8450x over previous
//
#include <hip/hip_runtime.h>
#include <math.h>

// Spherical voxelization: points [B,N,3] f32 -> hist [B,1,5,30,15] f32
// B=16, N=65536, bins = 5*30*15 = 2250.
// R9: R7's native-u32-atomic scheme (fp32 atomicAdd = CAS loop was the ~40us
// invariant), with the flush de-atomicized:
//   stage 1: LDS u32 hist (native ds_add_u32) -> plain coalesced u32 stores
//            to ws[block][bin]  (no memset, no global atomics)
//   stage 2: reduce 64 partials per (batch,bin) + fixed-point->float convert,
//            plain store to d_out.
// R8 lesson: NO agent-scope fences/atomics (per-XCD L2 non-coherence makes
// them L2-writeback heavyweights; 512 of them cost ~60us).

constexpr int RAD_N = 5, AZI_N = 30, ELE_N = 15;
constexpr int BINS  = RAD_N * AZI_N * ELE_N;   // 2250
constexpr int BLOCK = 256;
constexpr int PPT   = 4;                       // points per thread
constexpr int PPB   = BLOCK * PPT;             // 1024
constexpr float FX_SCALE = 2097152.0f;         // 2^21
constexpr float FX_INV   = 1.0f / 2097152.0f;

__device__ __forceinline__ float fast_atan2_02pi(float y, float x) {
    const float PI_F     = 3.14159265358979f;
    const float TWO_PI_F = 6.28318530717959f;
    const float HALF_PI  = 1.57079632679490f;
    float ax = fabsf(x), ay = fabsf(y);
    float mx = fmaxf(ax, ay), mn = fminf(ax, ay);
    float t  = mn * __builtin_amdgcn_rcpf(mx);
    float t2 = t * t;
    float p = -0.01172120f;
    p = __builtin_fmaf(p, t2,  0.05265332f);
    p = __builtin_fmaf(p, t2, -0.11643287f);
    p = __builtin_fmaf(p, t2,  0.19354346f);
    p = __builtin_fmaf(p, t2, -0.33262347f);
    p = __builtin_fmaf(p, t2,  0.99997726f);
    float th = t * p;                          // [0, pi/4]
    th = (ay > ax) ? (HALF_PI - th) : th;      // [0, pi/2]
    th = (x < 0.0f) ? (PI_F - th) : th;        // [0, pi]
    th = (y < 0.0f) ? (TWO_PI_F - th) : th;    // [0, 2pi)
    return th;
}

__device__ __forceinline__ float fast_acos(float x) {
    const float PI_F = 3.14159265358979f;
    float a = fabsf(x);
    float p = -0.0012624911f;
    p = __builtin_fmaf(p, a,  0.0066700901f);
    p = __builtin_fmaf(p, a, -0.0170881256f);
    p = __builtin_fmaf(p, a,  0.0308918810f);
    p = __builtin_fmaf(p, a, -0.0501743046f);
    p = __builtin_fmaf(p, a,  0.0889789874f);
    p = __builtin_fmaf(p, a, -0.2145988016f);
    p = __builtin_fmaf(p, a,  1.5707963050f);
    float s = __builtin_amdgcn_sqrtf(1.0f - a);
    float r = s * p;
    return (x < 0.0f) ? (PI_F - r) : r;
}

__device__ __forceinline__ unsigned to_fx(float w) {
    float v = __builtin_fmaf(w, FX_SCALE, 0.5f);
    return (unsigned)fmaxf(v, 0.0f);
}

__device__ __forceinline__ void process_point(float x, float y, float z,
                                              unsigned* hist) {
    const float TWO_PI_F = (float)(6.283185307179586);
    const float PI_F     = (float)(3.141592653589793);
    const float tr       = (float)(2.0 / 5.0);
    const float sr       = (float)(2.0 / 5.0 / 2.0);
    const float tr_p_sr  = (float)(0.4 + 0.2);
    const float rhi_lo   = (float)(2.0 - 0.2);
    const float DES_R_F  = 2.0f;
    const float ta       = (float)(6.283185307179586 / 30.0);
    const float te       = (float)(3.141592653589793 / 15.0);
    const float se       = (float)(3.141592653589793 / 30.0);
    const float te_p_se  = (float)(3.141592653589793 / 15.0 + 3.141592653589793 / 30.0);
    const float te075    = (float)(0.75 * (3.141592653589793 / 15.0));
    const float pi_m_se  = (float)(3.141592653589793 - 3.141592653589793 / 30.0);
    const float inv_tr   = (float)(5.0 / 2.0);
    const float inv_ta   = (float)(30.0 / 6.283185307179586);
    const float inv_te   = (float)(15.0 / 3.141592653589793);

    float r = __builtin_amdgcn_sqrtf(x * x + y * y + z * z);
    if (r > DES_R_F) return;   // all 8 weights exactly 0 in reference

    float azi = fast_atan2_02pi(y, x);
    float cz = z * __builtin_amdgcn_rcpf(fmaxf(r, 1e-12f));
    cz = fminf(fmaxf(cz, -1.0f), 1.0f);
    float ele = fast_acos(cz);

    // ---- radial ----
    int ra = (int)(r * inv_tr);
    if (ra > RAD_N - 1) ra = RAD_N - 1;
    float cra = ((float)ra + 0.5f) * tr;
    int rb = (r > cra) ? ra + 1 : ra - 1;
    rb = (rb < 0) ? 1 : ((rb > RAD_N - 1) ? RAD_N - 2 : rb);
    float dra = fabsf(r - cra);
    float drb = fabsf(r - ((float)rb + 0.5f) * tr);
    {
        bool lowR  = r < sr;
        bool highR = (r > rhi_lo);
        if (lowR) {
            dra = (dra <= sr) ? 0.0f : ((dra > tr && dra <= tr_p_sr) ? tr : dra);
            drb = (drb <= sr) ? 0.0f : ((drb > tr && drb <= tr_p_sr) ? tr : drb);
        }
        if (highR) {
            if (dra > tr && dra <= tr_p_sr) dra = tr;
            if (drb > tr && drb <= tr_p_sr) drb = tr;
        }
    }
    float wra = 1.0f - dra * inv_tr;
    float wrb = 1.0f - drb * inv_tr;

    // ---- azimuth (circular) ----
    int aa = (int)(azi * inv_ta);
    if (aa > AZI_N - 1) aa = AZI_N - 1;
    float caa = ((float)aa + 0.5f) * ta;
    int ab = (azi > caa) ? aa + 1 : aa - 1;
    ab = (ab < 0) ? AZI_N - 1 : ((ab > AZI_N - 1) ? 0 : ab);
    float daa = fabsf(azi - caa);
    daa = fminf(daa, TWO_PI_F - daa);
    float dab = fabsf(azi - ((float)ab + 0.5f) * ta);
    dab = fminf(dab, TWO_PI_F - dab);
    float waa = 1.0f - daa * inv_ta;
    float wab = 1.0f - dab * inv_ta;

    // ---- elevation ----
    int ea = (int)(ele * inv_te);
    if (ea > ELE_N - 1) ea = ELE_N - 1;
    float cea = ((float)ea + 0.5f) * te;
    int eb = (ele > cea) ? ea + 1 : ea - 1;
    eb = (eb < 0) ? 1 : ((eb > ELE_N - 1) ? ELE_N - 2 : eb);
    float dea = fabsf(ele - cea);
    float deb = fabsf(ele - ((float)eb + 0.5f) * te);
    {
        bool lowE  = ele < se;
        bool highE = (ele > pi_m_se) && (ele <= PI_F);
        if (lowE) {
            dea = (dea <= se) ? 0.0f : ((dea > te && dea <= te_p_se) ? te : dea);
            deb = (deb <= se) ? 0.0f : ((deb > te && deb <= te_p_se) ? te : deb);
        }
        if (highE) {
            dea = (dea <= te075) ? 0.0f : ((dea > te && dea <= te_p_se) ? te : dea);
            deb = (deb <= te075) ? 0.0f : ((deb > te && deb <= te_p_se) ? te : deb);
        }
    }
    float wea = 1.0f - dea * inv_te;
    float web = 1.0f - deb * inv_te;

    int rbase_a = ra * (AZI_N * ELE_N), rbase_b = rb * (AZI_N * ELE_N);
    int abase_a = aa * ELE_N,           abase_b = ab * ELE_N;
    float w_aa = wra * waa, w_ab = wra * wab;
    float w_ba = wrb * waa, w_bb = wrb * wab;

    atomicAdd(&hist[rbase_a + abase_a + ea], to_fx(w_aa * wea));
    atomicAdd(&hist[rbase_a + abase_a + eb], to_fx(w_aa * web));
    atomicAdd(&hist[rbase_a + abase_b + ea], to_fx(w_ab * wea));
    atomicAdd(&hist[rbase_a + abase_b + eb], to_fx(w_ab * web));
    atomicAdd(&hist[rbase_b + abase_a + ea], to_fx(w_ba * wea));
    atomicAdd(&hist[rbase_b + abase_a + eb], to_fx(w_ba * web));
    atomicAdd(&hist[rbase_b + abase_b + ea], to_fx(w_bb * wea));
    atomicAdd(&hist[rbase_b + abase_b + eb], to_fx(w_bb * web));
}

// Stage 1: LDS u32 hist -> plain coalesced stores to ws[block][bin]
__global__ __launch_bounds__(BLOCK) void voxel_store(
    const float* __restrict__ pts, unsigned* __restrict__ ws_u,
    int N, int blocksPerBatch)
{
    __shared__ unsigned hist[BINS];
    for (int j = threadIdx.x; j < BINS; j += BLOCK) hist[j] = 0u;
    __syncthreads();

    const int batch = blockIdx.x / blocksPerBatch;
    const int bib   = blockIdx.x % blocksPerBatch;
    const size_t batch_off = (size_t)batch * N;
    const int i0 = bib * PPB + (int)threadIdx.x * PPT;

    if (i0 + PPT <= N) {
        const float4* src = (const float4*)(pts + (batch_off + i0) * 3);
        float4 q0 = src[0];
        float4 q1 = src[1];
        float4 q2 = src[2];
        float X[PPT] = { q0.x, q0.w, q1.z, q2.y };
        float Y[PPT] = { q0.y, q1.x, q1.w, q2.z };
        float Z[PPT] = { q0.z, q1.y, q2.x, q2.w };
#pragma unroll
        for (int k = 0; k < PPT; ++k)
            process_point(X[k], Y[k], Z[k], hist);
    } else {
        for (int k = 0; k < PPT; ++k) {
            int i = i0 + k;
            if (i < N) {
                size_t p = (batch_off + i) * 3;
                process_point(pts[p], pts[p + 1], pts[p + 2], hist);
            }
        }
    }

    __syncthreads();
    unsigned* wb = ws_u + (size_t)blockIdx.x * BINS;
    for (int j = threadIdx.x; j < BINS; j += BLOCK) wb[j] = hist[j];
}

// Stage 2: out[batch][bin] = (sum_k ws[batch*bpb+k][bin]) * 2^-21
__global__ __launch_bounds__(BLOCK) void reduce_convert(
    const unsigned* __restrict__ ws_u, float* __restrict__ out,
    int blocksPerBatch, int total)
{
    int idx = blockIdx.x * BLOCK + (int)threadIdx.x;
    if (idx >= total) return;
    int batch = idx / BINS;
    int bin   = idx - batch * BINS;
    const unsigned* src = ws_u + (size_t)batch * blocksPerBatch * BINS + bin;
    unsigned s0 = 0u, s1 = 0u, s2 = 0u, s3 = 0u;
    int k = 0;
    for (; k + 3 < blocksPerBatch; k += 4) {
        unsigned a0 = src[(size_t)(k + 0) * BINS];
        unsigned a1 = src[(size_t)(k + 1) * BINS];
        unsigned a2 = src[(size_t)(k + 2) * BINS];
        unsigned a3 = src[(size_t)(k + 3) * BINS];
        s0 += a0; s1 += a1; s2 += a2; s3 += a3;
    }
    for (; k < blocksPerBatch; ++k) s0 += src[(size_t)k * BINS];
    out[idx] = (float)((s0 + s1) + (s2 + s3)) * FX_INV;
}

extern "C" void kernel_launch(void* const* d_in, const int* in_sizes, int n_in,
                              void* d_out, int out_size, void* d_ws, size_t ws_size,
                              hipStream_t stream) {
    const float* pts = (const float*)d_in[0];
    float* out = (float*)d_out;

    const int B = 16;
    int total = in_sizes[0] / 3;                 // B*N
    int N = total / B;                           // 65536
    int blocksPerBatch = (N + PPB - 1) / PPB;    // 64
    int grid = B * blocksPerBatch;               // 1024

    unsigned* ws_u = (unsigned*)d_ws;            // grid*BINS u32 = 9.2 MB
    voxel_store<<<dim3(grid), dim3(BLOCK), 0, stream>>>(pts, ws_u, N, blocksPerBatch);
    int rtotal = B * BINS;                       // 36000
    reduce_convert<<<dim3((rtotal + BLOCK - 1) / BLOCK), dim3(BLOCK), 0, stream>>>(
        ws_u, out, blocksPerBatch, rtotal);
}

// Round 10
// 69.007 us; speedup vs baseline: 1.8712x; 1.0142x over previous
//
#include <hip/hip_runtime.h>
#include <math.h>

// Spherical voxelization: points [B,N,3] f32 -> hist [B,1,5,30,15] f32
// B=16, N=65536, bins = 5*30*15 = 2250.
// R10: R9 structure (LDS u32 hist w/ native ds_add_u32 -> plain stores of
// partials -> reduce+convert), occupancy raised to the 32-wave/CU cap:
// BLOCK=512, PPT=2, grid 1024 -> 4 blocks/CU x 8 waves = 100% occupancy.
// (R5's occupancy test was masked by the fp32-atomic CAS serialization.)

constexpr int RAD_N = 5, AZI_N = 30, ELE_N = 15;
constexpr int BINS  = RAD_N * AZI_N * ELE_N;   // 2250
constexpr int BLOCK = 512;
constexpr int PPT   = 2;                       // points per thread
constexpr int PPB   = BLOCK * PPT;             // 1024
constexpr float FX_SCALE = 2097152.0f;         // 2^21
constexpr float FX_INV   = 1.0f / 2097152.0f;

__device__ __forceinline__ float fast_atan2_02pi(float y, float x) {
    const float PI_F     = 3.14159265358979f;
    const float TWO_PI_F = 6.28318530717959f;
    const float HALF_PI  = 1.57079632679490f;
    float ax = fabsf(x), ay = fabsf(y);
    float mx = fmaxf(ax, ay), mn = fminf(ax, ay);
    float t  = mn * __builtin_amdgcn_rcpf(mx);
    float t2 = t * t;
    float p = -0.01172120f;
    p = __builtin_fmaf(p, t2,  0.05265332f);
    p = __builtin_fmaf(p, t2, -0.11643287f);
    p = __builtin_fmaf(p, t2,  0.19354346f);
    p = __builtin_fmaf(p, t2, -0.33262347f);
    p = __builtin_fmaf(p, t2,  0.99997726f);
    float th = t * p;                          // [0, pi/4]
    th = (ay > ax) ? (HALF_PI - th) : th;      // [0, pi/2]
    th = (x < 0.0f) ? (PI_F - th) : th;        // [0, pi]
    th = (y < 0.0f) ? (TWO_PI_F - th) : th;    // [0, 2pi)
    return th;
}

__device__ __forceinline__ float fast_acos(float x) {
    const float PI_F = 3.14159265358979f;
    float a = fabsf(x);
    float p = -0.0012624911f;
    p = __builtin_fmaf(p, a,  0.0066700901f);
    p = __builtin_fmaf(p, a, -0.0170881256f);
    p = __builtin_fmaf(p, a,  0.0308918810f);
    p = __builtin_fmaf(p, a, -0.0501743046f);
    p = __builtin_fmaf(p, a,  0.0889789874f);
    p = __builtin_fmaf(p, a, -0.2145988016f);
    p = __builtin_fmaf(p, a,  1.5707963050f);
    float s = __builtin_amdgcn_sqrtf(1.0f - a);
    float r = s * p;
    return (x < 0.0f) ? (PI_F - r) : r;
}

__device__ __forceinline__ unsigned to_fx(float w) {
    float v = __builtin_fmaf(w, FX_SCALE, 0.5f);
    return (unsigned)fmaxf(v, 0.0f);
}

__device__ __forceinline__ void process_point(float x, float y, float z,
                                              unsigned* hist) {
    const float TWO_PI_F = (float)(6.283185307179586);
    const float PI_F     = (float)(3.141592653589793);
    const float tr       = (float)(2.0 / 5.0);
    const float sr       = (float)(2.0 / 5.0 / 2.0);
    const float tr_p_sr  = (float)(0.4 + 0.2);
    const float rhi_lo   = (float)(2.0 - 0.2);
    const float DES_R_F  = 2.0f;
    const float ta       = (float)(6.283185307179586 / 30.0);
    const float te       = (float)(3.141592653589793 / 15.0);
    const float se       = (float)(3.141592653589793 / 30.0);
    const float te_p_se  = (float)(3.141592653589793 / 15.0 + 3.141592653589793 / 30.0);
    const float te075    = (float)(0.75 * (3.141592653589793 / 15.0));
    const float pi_m_se  = (float)(3.141592653589793 - 3.141592653589793 / 30.0);
    const float inv_tr   = (float)(5.0 / 2.0);
    const float inv_ta   = (float)(30.0 / 6.283185307179586);
    const float inv_te   = (float)(15.0 / 3.141592653589793);

    float r = __builtin_amdgcn_sqrtf(x * x + y * y + z * z);
    if (r > DES_R_F) return;   // all 8 weights exactly 0 in reference

    float azi = fast_atan2_02pi(y, x);
    float cz = z * __builtin_amdgcn_rcpf(fmaxf(r, 1e-12f));
    cz = fminf(fmaxf(cz, -1.0f), 1.0f);
    float ele = fast_acos(cz);

    // ---- radial ----
    int ra = (int)(r * inv_tr);
    if (ra > RAD_N - 1) ra = RAD_N - 1;
    float cra = ((float)ra + 0.5f) * tr;
    int rb = (r > cra) ? ra + 1 : ra - 1;
    rb = (rb < 0) ? 1 : ((rb > RAD_N - 1) ? RAD_N - 2 : rb);
    float dra = fabsf(r - cra);
    float drb = fabsf(r - ((float)rb + 0.5f) * tr);
    {
        bool lowR  = r < sr;
        bool highR = (r > rhi_lo);
        if (lowR) {
            dra = (dra <= sr) ? 0.0f : ((dra > tr && dra <= tr_p_sr) ? tr : dra);
            drb = (drb <= sr) ? 0.0f : ((drb > tr && drb <= tr_p_sr) ? tr : drb);
        }
        if (highR) {
            if (dra > tr && dra <= tr_p_sr) dra = tr;
            if (drb > tr && drb <= tr_p_sr) drb = tr;
        }
    }
    float wra = 1.0f - dra * inv_tr;
    float wrb = 1.0f - drb * inv_tr;

    // ---- azimuth (circular) ----
    int aa = (int)(azi * inv_ta);
    if (aa > AZI_N - 1) aa = AZI_N - 1;
    float caa = ((float)aa + 0.5f) * ta;
    int ab = (azi > caa) ? aa + 1 : aa - 1;
    ab = (ab < 0) ? AZI_N - 1 : ((ab > AZI_N - 1) ? 0 : ab);
    float daa = fabsf(azi - caa);
    daa = fminf(daa, TWO_PI_F - daa);
    float dab = fabsf(azi - ((float)ab + 0.5f) * ta);
    dab = fminf(dab, TWO_PI_F - dab);
    float waa = 1.0f - daa * inv_ta;
    float wab = 1.0f - dab * inv_ta;

    // ---- elevation ----
    int ea = (int)(ele * inv_te);
    if (ea > ELE_N - 1) ea = ELE_N - 1;
    float cea = ((float)ea + 0.5f) * te;
    int eb = (ele > cea) ? ea + 1 : ea - 1;
    eb = (eb < 0) ? 1 : ((eb > ELE_N - 1) ? ELE_N - 2 : eb);
    float dea = fabsf(ele - cea);
    float deb = fabsf(ele - ((float)eb + 0.5f) * te);
    {
        bool lowE  = ele < se;
        bool highE = (ele > pi_m_se) && (ele <= PI_F);
        if (lowE) {
            dea = (dea <= se) ? 0.0f : ((dea > te && dea <= te_p_se) ? te : dea);
            deb = (deb <= se) ? 0.0f : ((deb > te && deb <= te_p_se) ? te : deb);
        }
        if (highE) {
            dea = (dea <= te075) ? 0.0f : ((dea > te && dea <= te_p_se) ? te : dea);
            deb = (deb <= te075) ? 0.0f : ((deb > te && deb <= te_p_se) ? te : deb);
        }
    }
    float wea = 1.0f - dea * inv_te;
    float web = 1.0f - deb * inv_te;

    int rbase_a = ra * (AZI_N * ELE_N), rbase_b = rb * (AZI_N * ELE_N);
    int abase_a = aa * ELE_N,           abase_b = ab * ELE_N;
    float w_aa = wra * waa, w_ab = wra * wab;
    float w_ba = wrb * waa, w_bb = wrb * wab;

    atomicAdd(&hist[rbase_a + abase_a + ea], to_fx(w_aa * wea));
    atomicAdd(&hist[rbase_a + abase_a + eb], to_fx(w_aa * web));
    atomicAdd(&hist[rbase_a + abase_b + ea], to_fx(w_ab * wea));
    atomicAdd(&hist[rbase_a + abase_b + eb], to_fx(w_ab * web));
    atomicAdd(&hist[rbase_b + abase_a + ea], to_fx(w_ba * wea));
    atomicAdd(&hist[rbase_b + abase_a + eb], to_fx(w_ba * web));
    atomicAdd(&hist[rbase_b + abase_b + ea], to_fx(w_bb * wea));
    atomicAdd(&hist[rbase_b + abase_b + eb], to_fx(w_bb * web));
}

// Stage 1: LDS u32 hist -> plain coalesced stores to ws[block][bin]
__global__ __launch_bounds__(BLOCK) void voxel_store(
    const float* __restrict__ pts, unsigned* __restrict__ ws_u,
    int N, int blocksPerBatch)
{
    __shared__ unsigned hist[BINS];
    for (int j = threadIdx.x; j < BINS; j += BLOCK) hist[j] = 0u;
    __syncthreads();

    const int batch = blockIdx.x / blocksPerBatch;
    const int bib   = blockIdx.x % blocksPerBatch;
    const size_t batch_off = (size_t)batch * N;
    const int i0 = bib * PPB + (int)threadIdx.x * PPT;

    if (i0 + PPT <= N) {
        // 2 points = 6 floats at byte offset 24*tid (8-aligned): 3x float2
        const float2* src = (const float2*)(pts + (batch_off + i0) * 3);
        float2 q0 = src[0];
        float2 q1 = src[1];
        float2 q2 = src[2];
        process_point(q0.x, q0.y, q1.x, hist);
        process_point(q1.y, q2.x, q2.y, hist);
    } else {
        for (int k = 0; k < PPT; ++k) {
            int i = i0 + k;
            if (i < N) {
                size_t p = (batch_off + i) * 3;
                process_point(pts[p], pts[p + 1], pts[p + 2], hist);
            }
        }
    }

    __syncthreads();
    unsigned* wb = ws_u + (size_t)blockIdx.x * BINS;
    for (int j = threadIdx.x; j < BINS; j += BLOCK) wb[j] = hist[j];
}

// Stage 2: out[batch][bin] = (sum_k ws[batch*bpb+k][bin]) * 2^-21
__global__ __launch_bounds__(256) void reduce_convert(
    const unsigned* __restrict__ ws_u, float* __restrict__ out,
    int blocksPerBatch, int total)
{
    int idx = blockIdx.x * 256 + (int)threadIdx.x;
    if (idx >= total) return;
    int batch = idx / BINS;
    int bin   = idx - batch * BINS;
    const unsigned* src = ws_u + (size_t)batch * blocksPerBatch * BINS + bin;
    unsigned s0 = 0u, s1 = 0u, s2 = 0u, s3 = 0u;
    int k = 0;
    for (; k + 3 < blocksPerBatch; k += 4) {
        unsigned a0 = src[(size_t)(k + 0) * BINS];
        unsigned a1 = src[(size_t)(k + 1) * BINS];
        unsigned a2 = src[(size_t)(k + 2) * BINS];
        unsigned a3 = src[(size_t)(k + 3) * BINS];
        s0 += a0; s1 += a1; s2 += a2; s3 += a3;
    }
    for (; k < blocksPerBatch; ++k) s0 += src[(size_t)k * BINS];
    out[idx] = (float)((s0 + s1) + (s2 + s3)) * FX_INV;
}

extern "C" void kernel_launch(void* const* d_in, const int* in_sizes, int n_in,
                              void* d_out, int out_size, void* d_ws, size_t ws_size,
                              hipStream_t stream) {
    const float* pts = (const float*)d_in[0];
    float* out = (float*)d_out;

    const int B = 16;
    int total = in_sizes[0] / 3;                 // B*N
    int N = total / B;                           // 65536
    int blocksPerBatch = (N + PPB - 1) / PPB;    // 64
    int grid = B * blocksPerBatch;               // 1024

    unsigned* ws_u = (unsigned*)d_ws;            // grid*BINS u32 = 9.2 MB
    voxel_store<<<dim3(grid), dim3(BLOCK), 0, stream>>>(pts, ws_u, N, blocksPerBatch);
    int rtotal = B * BINS;                       // 36000
    reduce_convert<<<dim3((rtotal + 255) / 256), dim3(256), 0, stream>>>(
        ws_u, out, blocksPerBatch, rtotal);
}